// Round 7
// baseline (455.118 us; speedup 1.0000x reference)
//
#include <hip/hip_runtime.h>

#define H 16
#define DK 64

typedef float vfloat4 __attribute__((ext_vector_type(4)));

// ---------------------------------------------------------------------------
// Kernel 1: per (b,h) precompute (unchanged — negligible runtime, verified)
//   R_K[e] = sum_d R[b,h,d]*WK_w[e,d] + WK_b[e]
//   R_V[e] = sum_d R[b,h,d]*WV_w[e,d] + WV_b[e]
//   u[d]   = sum_e WQ_w[e,d]*R_K[e]           (WQ folded into the gate)
//   c      = sum_e WQ_b[e]*R_K[e]
// ---------------------------------------------------------------------------
__global__ __launch_bounds__(64) void prep_kernel(
    const float* __restrict__ R,
    const float* __restrict__ WQ_w, const float* __restrict__ WQ_b,
    const float* __restrict__ WK_w, const float* __restrict__ WK_b,
    const float* __restrict__ WV_w, const float* __restrict__ WV_b,
    float* __restrict__ u, float* __restrict__ rv, float* __restrict__ c) {
    const int bh = blockIdx.x;           // b*H + h
    const int e  = threadIdx.x;          // 0..63
    __shared__ float r_s[DK];
    __shared__ float rk_s[DK];

    r_s[e] = R[bh * DK + e];             // R is (dps,1,H*DK) contiguous
    __syncthreads();

    float rk  = WK_b[e];
    float rvv = WV_b[e];
#pragma unroll
    for (int d = 0; d < DK; ++d) {
        rk  += r_s[d] * WK_w[e * DK + d];
        rvv += r_s[d] * WV_w[e * DK + d];
    }
    rk_s[e] = rk;
    rv[bh * DK + e] = rvv;
    __syncthreads();

    float uu = 0.f;
#pragma unroll
    for (int ee = 0; ee < DK; ++ee) uu += WQ_w[ee * DK + e] * rk_s[ee];
    u[bh * DK + e] = uu;

    if (e == 0) {
        float cc = 0.f;
        for (int ee = 0; ee < DK; ++ee) cc += WQ_b[ee] * rk_s[ee];
        c[bh] = cc;
    }
}

// ---------------------------------------------------------------------------
// Kernel 2: streaming pass over S — DENSE unconditional reads.
//
// Session ledger (calibrated decomposition: total = 2x161.7 fill + 3 prep + fused):
//   r1  dummy-redirect reads + nt stores      : fused ~114 us (~735 MB -> 6.4 TB/s, BUS-SATURATED on wasted bytes)
//   r4  pipelined + nt stores                 : fused 187.6 us (REGRESSED; nt WRITE_SIZE 2.18x)
//   r5  dummy-redirect reads + regular stores : fused ~100 us (~420 MB -> 4.2 TB/s, NOT bus-limited)
// => after the store fix a ~100us non-byte limiter emerged. Issue-rate/DS/VALU/TLP
//    arithmetic all bound <=10us; surviving theory = DRAM efficiency loss on the
//    50%-density mask-gapped read stream (dense fills/copy hit 6.3-6.5 TB/s).
//
// This round's single variable: read EVERY row at its true address (dense
// stream, no dummy redirect, no mask->address dependency; loads issue
// immediately). Mask gates only the output select. +134 MB reads, but dense.
// ---------------------------------------------------------------------------
#define ROWS_PER_BLOCK 16

__global__ __launch_bounds__(256) void fused_kernel(
    const float* __restrict__ S, const int* __restrict__ S_mas,
    const float* __restrict__ u, const float* __restrict__ rv,
    const float* __restrict__ c, float* __restrict__ out,
    int seq_len, int blocks_per_batch) {
    const int t = threadIdx.x;
    const int h = t >> 4;                          // head 0..15
    const int b = blockIdx.x / blocks_per_batch;
    const int srow0 = (blockIdx.x % blocks_per_batch) * ROWS_PER_BLOCK;
    const int d_model = H * DK;                    // 1024

    const int bh = b * H + h;
    const vfloat4 u4  = *(const vfloat4*)(u  + bh * DK + (t & 15) * 4);
    const vfloat4 rv4 = *(const vfloat4*)(rv + bh * DK + (t & 15) * 4);
    const float   ch  = c[bh];

    const size_t base = (size_t)b * seq_len * d_model + (size_t)srow0 * d_model + t * 4;
    const float* srow = S + base;
    float*       orow = out + base;
    const int*   mrow = S_mas + (size_t)b * seq_len + srow0;

    // Dense read: ALL rows, true addresses, no dependency on the mask.
    // These issue first and back-to-back (16 in flight per wave).
    vfloat4 sdat[ROWS_PER_BLOCK];
#pragma unroll
    for (int r = 0; r < ROWS_PER_BLOCK; ++r)
        sdat[r] = *(const vfloat4*)(srow + (size_t)r * d_model);

    // Mask loads issue in parallel with the S loads (independent).
    int m[ROWS_PER_BLOCK];
#pragma unroll
    for (int r = 0; r < ROWS_PER_BLOCK; ++r) m[r] = mrow[r];

#pragma unroll
    for (int r = 0; r < ROWS_PER_BLOCK; ++r) {
        const vfloat4 s4 = sdat[r];
        float p = s4.x * u4.x + s4.y * u4.y + s4.z * u4.z + s4.w * u4.w;
        p += __shfl_xor(p, 1);
        p += __shfl_xor(p, 2);
        p += __shfl_xor(p, 4);
        p += __shfl_xor(p, 8);
        const float beta = p + ch;
        const bool live = (m[r] != 0);
        vfloat4 o4;
        o4.x = live ? rv4.x * beta : 0.f;
        o4.y = live ? rv4.y * beta : 0.f;
        o4.z = live ? rv4.z * beta : 0.f;
        o4.w = live ? rv4.w * beta : 0.f;
        *(vfloat4*)(orow + (size_t)r * d_model) = o4;   // regular store: L2 merges full lines
    }
}

extern "C" void kernel_launch(void* const* d_in, const int* in_sizes, int n_in,
                              void* d_out, int out_size, void* d_ws, size_t ws_size,
                              hipStream_t stream) {
    const float* S     = (const float*)d_in[0];
    const float* R     = (const float*)d_in[1];
    const int*   S_mas = (const int*)d_in[2];
    // d_in[3] = R_mas (dead in reference output)
    const float* WQ_w  = (const float*)d_in[4];
    const float* WQ_b  = (const float*)d_in[5];
    const float* WK_w  = (const float*)d_in[6];
    const float* WK_b  = (const float*)d_in[7];
    const float* WV_w  = (const float*)d_in[8];
    const float* WV_b  = (const float*)d_in[9];
    float* out = (float*)d_out;

    const int d_model = H * DK;                        // 1024
    const int dps     = in_sizes[1] / d_model;         // 32
    const int seq_len = in_sizes[0] / (dps * d_model); // 2048

    float* u_ws  = (float*)d_ws;                       // dps*H*DK floats
    float* rv_ws = u_ws + (size_t)dps * H * DK;        // dps*H*DK floats
    float* c_ws  = rv_ws + (size_t)dps * H * DK;       // dps*H floats

    prep_kernel<<<dps * H, 64, 0, stream>>>(R, WQ_w, WQ_b, WK_w, WK_b, WV_w, WV_b,
                                            u_ws, rv_ws, c_ws);

    const int blocks_per_batch = seq_len / ROWS_PER_BLOCK;   // 128
    fused_kernel<<<dps * blocks_per_batch, 256, 0, stream>>>(
        S, S_mas, u_ws, rv_ws, c_ws, out, seq_len, blocks_per_batch);
}

// Round 10
// 447.107 us; speedup vs baseline: 1.0179x; 1.0179x over previous
//
#include <hip/hip_runtime.h>

#define H 16
#define DK 64

typedef float vfloat4 __attribute__((ext_vector_type(4)));

// ---------------------------------------------------------------------------
// Kernel 1: per (b,h) precompute (unchanged — negligible runtime, verified)
// ---------------------------------------------------------------------------
__global__ __launch_bounds__(64) void prep_kernel(
    const float* __restrict__ R,
    const float* __restrict__ WQ_w, const float* __restrict__ WQ_b,
    const float* __restrict__ WK_w, const float* __restrict__ WK_b,
    const float* __restrict__ WV_w, const float* __restrict__ WV_b,
    float* __restrict__ u, float* __restrict__ rv, float* __restrict__ c) {
    const int bh = blockIdx.x;           // b*H + h
    const int e  = threadIdx.x;          // 0..63
    __shared__ float r_s[DK];
    __shared__ float rk_s[DK];

    r_s[e] = R[bh * DK + e];             // R is (dps,1,H*DK) contiguous
    __syncthreads();

    float rk  = WK_b[e];
    float rvv = WV_b[e];
#pragma unroll
    for (int d = 0; d < DK; ++d) {
        rk  += r_s[d] * WK_w[e * DK + d];
        rvv += r_s[d] * WV_w[e * DK + d];
    }
    rk_s[e] = rk;
    rv[bh * DK + e] = rvv;
    __syncthreads();

    float uu = 0.f;
#pragma unroll
    for (int ee = 0; ee < DK; ++ee) uu += WQ_w[ee * DK + e] * rk_s[ee];
    u[bh * DK + e] = uu;

    if (e == 0) {
        float cc = 0.f;
        for (int ee = 0; ee < DK; ++ee) cc += WQ_b[ee] * rk_s[ee];
        c[bh] = cc;
    }
}

// ---------------------------------------------------------------------------
// Kernel 2: dense NT reads + regular stores.
//
// Session ledger (total = 2x~163 fill + 3 prep + fused):
//   r1 redirect reads(reg) + NT stores : ~735 MB, fused ~110us -> 6.4+ TB/s BUS-SATURATED (writes 2.18x amplified)
//   r4 scalar-branch skip  + NT stores : 724 MB, 187.6us -> 3.86 TB/s (per-row lds->readfirstlane->branch broke load batching)
//   r5 redirect reads(reg) + reg stores: ~420 MB, fused ~95-105us -> ~4.4 TB/s
//   r7 dense   reads(reg) + reg stores: ~555 MB, fused ~120-135us -> ~4.5 TB/s
// => gappy-read theory DEAD (r7). Surviving theory: mixed read+write through
//    L2 caps at ~4.5 TB/s (one-direction streams hit 6.4-6.5: fills = writes
//    through L2; r1 = reads through L2, writes bypassing via nt).
//
// THIS ROUND'S SINGLE VARIABLE (vs r7): loads become non-temporal ->
// reads bypass L2, L2 becomes write-only like the 6.5 TB/s fills. S has
// zero reuse so nt is semantically right. Dense nt reads have no burst
// waste (4KB rows >> 32B DRAM bursts). Stores stay regular (line-merged,
// 1.00x bytes — r4 proved nt stores amplify 2.18x).
// ---------------------------------------------------------------------------
#define ROWS_PER_BLOCK 16

__global__ __launch_bounds__(256) void fused_kernel(
    const float* __restrict__ S, const int* __restrict__ S_mas,
    const float* __restrict__ u, const float* __restrict__ rv,
    const float* __restrict__ c, float* __restrict__ out,
    int seq_len, int blocks_per_batch) {
    const int t = threadIdx.x;
    const int h = t >> 4;                          // head 0..15
    const int b = blockIdx.x / blocks_per_batch;
    const int srow0 = (blockIdx.x % blocks_per_batch) * ROWS_PER_BLOCK;
    const int d_model = H * DK;                    // 1024

    const int bh = b * H + h;
    const vfloat4 u4  = *(const vfloat4*)(u  + bh * DK + (t & 15) * 4);
    const vfloat4 rv4 = *(const vfloat4*)(rv + bh * DK + (t & 15) * 4);
    const float   ch  = c[bh];

    const size_t base = (size_t)b * seq_len * d_model + (size_t)srow0 * d_model + t * 4;
    const float* srow = S + base;
    float*       orow = out + base;
    const int*   mrow = S_mas + (size_t)b * seq_len + srow0;

    // Dense NT read: ALL rows, true addresses, mask-independent, 16 in
    // flight per wave, bypassing L2.
    vfloat4 sdat[ROWS_PER_BLOCK];
#pragma unroll
    for (int r = 0; r < ROWS_PER_BLOCK; ++r)
        sdat[r] = __builtin_nontemporal_load(
            (const vfloat4*)(srow + (size_t)r * d_model));

    // Mask loads issue in parallel (independent; tiny, leave them cached).
    int m[ROWS_PER_BLOCK];
#pragma unroll
    for (int r = 0; r < ROWS_PER_BLOCK; ++r) m[r] = mrow[r];

#pragma unroll
    for (int r = 0; r < ROWS_PER_BLOCK; ++r) {
        const vfloat4 s4 = sdat[r];
        float p = s4.x * u4.x + s4.y * u4.y + s4.z * u4.z + s4.w * u4.w;
        p += __shfl_xor(p, 1);
        p += __shfl_xor(p, 2);
        p += __shfl_xor(p, 4);
        p += __shfl_xor(p, 8);
        const float beta = p + ch;
        const bool live = (m[r] != 0);
        vfloat4 o4;
        o4.x = live ? rv4.x * beta : 0.f;
        o4.y = live ? rv4.y * beta : 0.f;
        o4.z = live ? rv4.z * beta : 0.f;
        o4.w = live ? rv4.w * beta : 0.f;
        *(vfloat4*)(orow + (size_t)r * d_model) = o4;   // regular store: L2 merges full lines
    }
}

extern "C" void kernel_launch(void* const* d_in, const int* in_sizes, int n_in,
                              void* d_out, int out_size, void* d_ws, size_t ws_size,
                              hipStream_t stream) {
    const float* S     = (const float*)d_in[0];
    const float* R     = (const float*)d_in[1];
    const int*   S_mas = (const int*)d_in[2];
    // d_in[3] = R_mas (dead in reference output)
    const float* WQ_w  = (const float*)d_in[4];
    const float* WQ_b  = (const float*)d_in[5];
    const float* WK_w  = (const float*)d_in[6];
    const float* WK_b  = (const float*)d_in[7];
    const float* WV_w  = (const float*)d_in[8];
    const float* WV_b  = (const float*)d_in[9];
    float* out = (float*)d_out;

    const int d_model = H * DK;                        // 1024
    const int dps     = in_sizes[1] / d_model;         // 32
    const int seq_len = in_sizes[0] / (dps * d_model); // 2048

    float* u_ws  = (float*)d_ws;                       // dps*H*DK floats
    float* rv_ws = u_ws + (size_t)dps * H * DK;        // dps*H*DK floats
    float* c_ws  = rv_ws + (size_t)dps * H * DK;       // dps*H floats

    prep_kernel<<<dps * H, 64, 0, stream>>>(R, WQ_w, WQ_b, WK_w, WK_b, WV_w, WV_b,
                                            u_ws, rv_ws, c_ws);

    const int blocks_per_batch = seq_len / ROWS_PER_BLOCK;   // 128
    fused_kernel<<<dps * blocks_per_batch, 256, 0, stream>>>(
        S, S_mas, u_ws, rv_ws, c_ws, out, seq_len, blocks_per_batch);
}

// Round 12
// 444.915 us; speedup vs baseline: 1.0229x; 1.0049x over previous
//
#include <hip/hip_runtime.h>

#define H 16
#define DK 64

typedef float vfloat4 __attribute__((ext_vector_type(4)));

// ---------------------------------------------------------------------------
// Session ledger (fused = total - 2x163.5 fill - 3 prep):
//   r1/r2 reads-via-L2 + NT stores   : ~724 MB -> ~112us = 6.5 TB/s (writes 2.18x amplified)
//   r4    pipelined    + NT stores   : 187.6us (schedule regression)
//   r5    redirect rd  + reg stores  : ~413 MB -> ~98us  = 4.2 TB/s   [best total 425.2]
//   r7    dense rd     + reg stores  : ~555 MB -> ~128us = 4.3 TB/s
//   r10   dense NT rd  + reg stores  : ~555 MB -> ~120us = 4.6 TB/s
// => Wall isn't DRAM direction-mixing (r1 is bidirectional at 6.5). It's the
//    WRITE PATH: writes through L2 with concurrent read misses -> 4.2-4.6;
//    writes bypassing L2 (nt) or read-free (fills) -> 6.5. TCC contention.
// THIS ROUND: split into two single-direction phases.
//   A (gate):   read S (mask-skip), write 4MB beta (masks folded in).
//   B (expand): read beta+rv (tiny/L2), write all 268MB of out. Fill-like.
// ---------------------------------------------------------------------------

// Kernel 1: per (b,h) precompute (unchanged — negligible runtime, verified)
__global__ __launch_bounds__(64) void prep_kernel(
    const float* __restrict__ R,
    const float* __restrict__ WQ_w, const float* __restrict__ WQ_b,
    const float* __restrict__ WK_w, const float* __restrict__ WK_b,
    const float* __restrict__ WV_w, const float* __restrict__ WV_b,
    float* __restrict__ u, float* __restrict__ rv, float* __restrict__ c) {
    const int bh = blockIdx.x;           // b*H + h
    const int e  = threadIdx.x;          // 0..63
    __shared__ float r_s[DK];
    __shared__ float rk_s[DK];

    r_s[e] = R[bh * DK + e];
    __syncthreads();

    float rk  = WK_b[e];
    float rvv = WV_b[e];
#pragma unroll
    for (int d = 0; d < DK; ++d) {
        rk  += r_s[d] * WK_w[e * DK + d];
        rvv += r_s[d] * WV_w[e * DK + d];
    }
    rk_s[e] = rk;
    rv[bh * DK + e] = rvv;
    __syncthreads();

    float uu = 0.f;
#pragma unroll
    for (int ee = 0; ee < DK; ++ee) uu += WQ_w[ee * DK + e] * rk_s[ee];
    u[bh * DK + e] = uu;

    if (e == 0) {
        float cc = 0.f;
        for (int ee = 0; ee < DK; ++ee) cc += WQ_b[ee] * rk_s[ee];
        c[bh] = cc;
    }
}

#define ROWS_PER_BLOCK 16

// ---------------------------------------------------------------------------
// Phase A: gate. Read-dominated (139 MB in, 4 MB out).
// r5-proven structure: mask loads hoisted, masked rows redirect their load
// to the block's row 0 (coalesced, L2-hit), result select. beta=0 for
// masked rows so phase B needs no masks at all.
// ---------------------------------------------------------------------------
__global__ __launch_bounds__(256) void gate_kernel(
    const float* __restrict__ S, const int* __restrict__ S_mas,
    const float* __restrict__ u, const float* __restrict__ c,
    float* __restrict__ beta, int seq_len, int blocks_per_batch) {
    const int t = threadIdx.x;
    const int h = t >> 4;                          // head 0..15
    const int b = blockIdx.x / blocks_per_batch;
    const int srow0 = (blockIdx.x % blocks_per_batch) * ROWS_PER_BLOCK;
    const int d_model = H * DK;                    // 1024

    const int bh = b * H + h;
    const vfloat4 u4 = *(const vfloat4*)(u + bh * DK + (t & 15) * 4);
    const float  ch  = c[bh];

    const size_t base = (size_t)b * seq_len * d_model + (size_t)srow0 * d_model + t * 4;
    const float* srow = S + base;
    const int*   mrow = S_mas + (size_t)b * seq_len + srow0;

    int m[ROWS_PER_BLOCK];
#pragma unroll
    for (int r = 0; r < ROWS_PER_BLOCK; ++r) m[r] = mrow[r];

    vfloat4 sdat[ROWS_PER_BLOCK];
#pragma unroll
    for (int r = 0; r < ROWS_PER_BLOCK; ++r) {
        const size_t off = (m[r] != 0) ? (size_t)r * d_model : 0;
        sdat[r] = *(const vfloat4*)(srow + off);
    }

    float* brow = beta + ((size_t)b * seq_len + srow0) * H + h;
#pragma unroll
    for (int r = 0; r < ROWS_PER_BLOCK; ++r) {
        const vfloat4 s4 = sdat[r];
        float p = s4.x * u4.x + s4.y * u4.y + s4.z * u4.z + s4.w * u4.w;
        p += __shfl_xor(p, 1);
        p += __shfl_xor(p, 2);
        p += __shfl_xor(p, 4);
        p += __shfl_xor(p, 8);
        const float bv = (m[r] != 0) ? (p + ch) : 0.f;
        if ((t & 15) == 0) brow[(size_t)r * H] = bv;   // one writer per head
    }
}

// ---------------------------------------------------------------------------
// Phase B: expand. Write-dominated (268 MB out; ~8 MB beta + L2-resident rv
// in). out[row, h*64+e] = rv[bh][e] * beta[row][h]. Branch-free, fill-like.
// ---------------------------------------------------------------------------
__global__ __launch_bounds__(256) void expand_kernel(
    const float* __restrict__ rv, const float* __restrict__ beta,
    float* __restrict__ out, int seq_len, int blocks_per_batch) {
    const int t = threadIdx.x;
    const int h = t >> 4;
    const int b = blockIdx.x / blocks_per_batch;
    const int srow0 = (blockIdx.x % blocks_per_batch) * ROWS_PER_BLOCK;
    const int d_model = H * DK;                    // 1024

    const int bh = b * H + h;
    const vfloat4 rv4 = *(const vfloat4*)(rv + bh * DK + (t & 15) * 4);

    const float* brow = beta + ((size_t)b * seq_len + srow0) * H + h;
    float bt[ROWS_PER_BLOCK];
#pragma unroll
    for (int r = 0; r < ROWS_PER_BLOCK; ++r) bt[r] = brow[(size_t)r * H];

    float* orow = out + (size_t)b * seq_len * d_model + (size_t)srow0 * d_model + t * 4;
#pragma unroll
    for (int r = 0; r < ROWS_PER_BLOCK; ++r) {
        vfloat4 o4;
        o4.x = rv4.x * bt[r]; o4.y = rv4.y * bt[r];
        o4.z = rv4.z * bt[r]; o4.w = rv4.w * bt[r];
        *(vfloat4*)(orow + (size_t)r * d_model) = o4;
    }
}

extern "C" void kernel_launch(void* const* d_in, const int* in_sizes, int n_in,
                              void* d_out, int out_size, void* d_ws, size_t ws_size,
                              hipStream_t stream) {
    const float* S     = (const float*)d_in[0];
    const float* R     = (const float*)d_in[1];
    const int*   S_mas = (const int*)d_in[2];
    // d_in[3] = R_mas (dead in reference output)
    const float* WQ_w  = (const float*)d_in[4];
    const float* WQ_b  = (const float*)d_in[5];
    const float* WK_w  = (const float*)d_in[6];
    const float* WK_b  = (const float*)d_in[7];
    const float* WV_w  = (const float*)d_in[8];
    const float* WV_b  = (const float*)d_in[9];
    float* out = (float*)d_out;

    const int d_model = H * DK;                        // 1024
    const int dps     = in_sizes[1] / d_model;         // 32
    const int seq_len = in_sizes[0] / (dps * d_model); // 2048

    // Workspace layout: u (128KB) | rv (128KB) | c (2KB) | beta (4MB).
    // The harness's 1 GiB re-poison fills indicate ws_size >> 5 MB.
    float* u_ws    = (float*)d_ws;
    float* rv_ws   = u_ws + (size_t)dps * H * DK;
    float* c_ws    = rv_ws + (size_t)dps * H * DK;
    float* beta_ws = c_ws + (size_t)dps * H;

    prep_kernel<<<dps * H, 64, 0, stream>>>(R, WQ_w, WQ_b, WK_w, WK_b, WV_w, WV_b,
                                            u_ws, rv_ws, c_ws);

    const int blocks_per_batch = seq_len / ROWS_PER_BLOCK;   // 128
    gate_kernel<<<dps * blocks_per_batch, 256, 0, stream>>>(
        S, S_mas, u_ws, c_ws, beta_ws, seq_len, blocks_per_batch);
    expand_kernel<<<dps * blocks_per_batch, 256, 0, stream>>>(
        rv_ws, beta_ws, out, seq_len, blocks_per_batch);
}